// Round 5
// baseline (3928.856 us; speedup 1.0000x reference)
//
#include <hip/hip_runtime.h>

typedef unsigned short u16;

// ---- problem constants ----
static constexpr int cB   = 32;
static constexpr int cC   = 768;
static constexpr int cD   = 512;
static constexpr int cNH  = 4;
static constexpr int cHD  = 192;   // C/NH
static constexpr int cFHW = 576;   // 24*24
static constexpr int cC3  = 2304;  // 3*C
static constexpr int cQ   = 8;     // quarter-batch

__device__ inline float us2f(u16 s) {
    union { unsigned int u; float f; } v; v.u = ((unsigned int)s) << 16; return v.f;
}
// flag-dispatched load from a raw d_in pointer: bf16 (flag 0) or fp32 (flag 1)
__device__ inline float ldflex(const void* p, size_t i, int isf32) {
    return isf32 ? ((const float*)p)[i] : us2f(((const u16*)p)[i]);
}

// dtype probe: fp32 ones -> u16[0]=0x0000 (low mantissa half); bf16 ones -> 0x3F80.
__global__ void detect_kernel(const u16* __restrict__ raw, int* __restrict__ flags) {
    flags[0] = (raw[0] == 0x3F80u) ? 0 : 1;
}

// canonicalize one input array to fp32
__global__ __launch_bounds__(256) void conv_in_kernel(
    const void* __restrict__ src, float* __restrict__ dst, int n, const int* __restrict__ flags)
{
    const int isf = flags[0];
    const int i = blockIdx.x * 256 + threadIdx.x;
    if (i < n) dst[i] = ldflex(src, i, isf);
}

// ============================================================
// txt LN (eps 1e-5) + qkv_txt GEMM: (B,512) -> (B,2304) fp32
// ============================================================
__global__ __launch_bounds__(256) void txt_qkv_kernel(
    const float* __restrict__ txt, const float* __restrict__ gw, const float* __restrict__ gb,
    const float* __restrict__ W, float* __restrict__ out)
{
    __shared__ float tln[cD];
    __shared__ float red[8];
    const int b = blockIdx.x, tid = threadIdx.x;
    const float v0 = txt[(size_t)b * cD + tid];
    const float v1 = txt[(size_t)b * cD + 256 + tid];
    float s = v0 + v1, ss = v0 * v0 + v1 * v1;
    #pragma unroll
    for (int o = 1; o < 64; o <<= 1) { s += __shfl_xor(s, o, 64); ss += __shfl_xor(ss, o, 64); }
    const int wid = tid >> 6, lane = tid & 63;
    if (lane == 0) { red[wid] = s; red[4 + wid] = ss; }
    __syncthreads();
    s  = red[0] + red[1] + red[2] + red[3];
    ss = red[4] + red[5] + red[6] + red[7];
    const float mean = s * (1.f / cD);
    const float var  = fmaxf(ss * (1.f / cD) - mean * mean, 0.f);
    const float r = rsqrtf(var + 1e-5f);
    tln[tid]       = (v0 - mean) * r * gw[tid]       + gb[tid];
    tln[tid + 256] = (v1 - mean) * r * gw[tid + 256] + gb[tid + 256];
    __syncthreads();
    #pragma unroll 1
    for (int j = 0; j < 9; j++) {
        const int o = tid + j * 256;
        const float4* wr = (const float4*)(W + (size_t)o * cD);
        float acc = 0.f;
        #pragma unroll 4
        for (int d4 = 0; d4 < cD / 4; d4++) {
            const float4 wv = wr[d4];
            const float* tp = &tln[d4 * 4];
            acc += tp[0] * wv.x + tp[1] * wv.y + tp[2] * wv.z + tp[3] * wv.w;
        }
        out[(size_t)b * cC3 + o] = acc;
    }
}

// ============================================================
// channel LayerNorm over C (eps 1e-6), fp32 out.
// RAW=1: x is raw d_in (flag dtype), xoff = b0*C*FHW element offset.
// ============================================================
template <int RAW>
__global__ __launch_bounds__(256) void ln2d_kernel(
    const void* __restrict__ x, size_t xoff, const float* __restrict__ w,
    const float* __restrict__ bias, float* __restrict__ out, const int* __restrict__ flags)
{
    const int isf = RAW ? flags[0] : 1;
    const int b = blockIdx.y;
    const int l = threadIdx.x & 63;
    const int f = (blockIdx.x << 6) + l;
    const int c4 = threadIdx.x >> 6;
    const size_t base = (size_t)b * cC * cFHW + f;
    const size_t rbase = RAW ? (xoff + base) : base;
    float s = 0.f, ss = 0.f;
    for (int c = c4; c < cC; c += 4) {
        float v = RAW ? ldflex(x, rbase + (size_t)c * cFHW, isf)
                      : ((const float*)x)[base + (size_t)c * cFHW];
        s += v; ss += v * v;
    }
    __shared__ float S[4][64], SS[4][64];
    S[c4][l] = s; SS[c4][l] = ss;
    __syncthreads();
    const float sum  = S[0][l] + S[1][l] + S[2][l] + S[3][l];
    const float ssum = SS[0][l] + SS[1][l] + SS[2][l] + SS[3][l];
    const float mean = sum * (1.f / cC);
    const float var  = fmaxf(ssum * (1.f / cC) - mean * mean, 0.f);
    const float r = rsqrtf(var + 1e-6f);
    for (int c = c4; c < cC; c += 4) {
        float v = RAW ? ldflex(x, rbase + (size_t)c * cFHW, isf)
                      : ((const float*)x)[base + (size_t)c * cFHW];
        out[base + (size_t)c * cFHW] = w[c] * ((v - mean) * r) + bias[c];
    }
}

// ============================================================
// 1x1-conv GEMM: out[b,m,n] = sum_k W[m,k] * X[b,k,n]   (N=576), fp32
// EPI 0: f32 out = acc
// EPI 1: f32 out = acc + bias_m + resRaw[resOff+o] (flag dtype)
// EPI 2: f32 out = acc + resF[o]      (final: write fp32 to d_out!)
// ============================================================
template <int EPI>
__global__ __launch_bounds__(256) void conv_gemm(
    const float* __restrict__ W, const float* __restrict__ X, float* __restrict__ outp,
    const float* __restrict__ bias_m, const void* __restrict__ resRaw, size_t resOff,
    const float* __restrict__ resF, int M, int K, const int* __restrict__ flags)
{
    const int n0 = blockIdx.x * 64, m0 = blockIdx.y * 64, b = blockIdx.z;
    __shared__ __align__(16) float At[16][68];  // At[k][m]
    __shared__ __align__(16) float Bt[16][68];  // Bt[k][n]
    const int tid = threadIdx.x;
    const int ty = tid >> 4, tx = tid & 15;
    float acc[4][4] = {};
    const size_t xbase = (size_t)b * K * cFHW + n0;
    for (int k0 = 0; k0 < K; k0 += 16) {
        {   // W tile: 64(m) x 16(k), float4 loads
            const int row = tid >> 2, kq = tid & 3;
            const float4 wv = *(const float4*)(W + (size_t)(m0 + row) * K + k0 + kq * 4);
            At[kq * 4 + 0][row] = wv.x;
            At[kq * 4 + 1][row] = wv.y;
            At[kq * 4 + 2][row] = wv.z;
            At[kq * 4 + 3][row] = wv.w;
            // X tile: 16(k) x 64(n)
            const int xn = tid & 63, xk = tid >> 6;
            #pragma unroll
            for (int p = 0; p < 4; p++) {
                const int kk = xk + p * 4;
                Bt[kk][xn] = X[xbase + (size_t)(k0 + kk) * cFHW + xn];
            }
        }
        __syncthreads();
        #pragma unroll
        for (int kk = 0; kk < 16; kk++) {
            const float4 av = *(const float4*)&At[kk][ty * 4];
            const float4 bv = *(const float4*)&Bt[kk][tx * 4];
            acc[0][0] += av.x * bv.x; acc[0][1] += av.x * bv.y; acc[0][2] += av.x * bv.z; acc[0][3] += av.x * bv.w;
            acc[1][0] += av.y * bv.x; acc[1][1] += av.y * bv.y; acc[1][2] += av.y * bv.z; acc[1][3] += av.y * bv.w;
            acc[2][0] += av.z * bv.x; acc[2][1] += av.z * bv.y; acc[2][2] += av.z * bv.z; acc[2][3] += av.z * bv.w;
            acc[3][0] += av.w * bv.x; acc[3][1] += av.w * bv.y; acc[3][2] += av.w * bv.z; acc[3][3] += av.w * bv.w;
        }
        __syncthreads();
    }
    const size_t obase = ((size_t)b * M + m0 + ty * 4) * cFHW + n0 + tx * 4;
    const int isf = (EPI == 1) ? flags[0] : 1;
    #pragma unroll
    for (int i = 0; i < 4; i++) {
        const size_t o = obase + (size_t)i * cFHW;
        if constexpr (EPI == 0) {
            *(float4*)&outp[o] = make_float4(acc[i][0], acc[i][1], acc[i][2], acc[i][3]);
        } else if constexpr (EPI == 1) {
            const float bm = bias_m[m0 + ty * 4 + i];
            float4 v;
            v.x = acc[i][0] + bm + ldflex(resRaw, resOff + o + 0, isf);
            v.y = acc[i][1] + bm + ldflex(resRaw, resOff + o + 1, isf);
            v.z = acc[i][2] + bm + ldflex(resRaw, resOff + o + 2, isf);
            v.w = acc[i][3] + bm + ldflex(resRaw, resOff + o + 3, isf);
            *(float4*)&outp[o] = v;
        } else {
            float4 v;
            v.x = acc[i][0] + resF[o + 0];
            v.y = acc[i][1] + resF[o + 1];
            v.z = acc[i][2] + resF[o + 2];
            v.w = acc[i][3] + resF[o + 3];
            *(float4*)&outp[o] = v;
        }
    }
}

// ============================================================
// attention stats: per (b_local,n,h) -> a1,m1,1/Z1,a2,m2,1/Z2
// ============================================================
__global__ __launch_bounds__(64) void attn_stats_kernel(
    const float* __restrict__ qkv, const float* __restrict__ tq, float* __restrict__ stats)
{
    const int idx = blockIdx.x;
    const int h = idx % cHD;
    const int bn = idx / cHD;
    const int n = bn & 3, b = bn >> 2;
    const int lane = threadIdx.x;
    const float* qrow = qkv + ((size_t)b * cC3 + n * cHD + h) * cFHW;
    const float* krow = qkv + ((size_t)b * cC3 + cC + n * cHD + h) * cFHW;
    float ssk = 0.f, mink = 3.0e38f, maxk = -3.0e38f;
    float ssq = 0.f, minq = 3.0e38f, maxq = -3.0e38f;
    for (int f = lane; f < cFHW; f += 64) {
        const float kv = krow[f]; ssk += kv * kv; maxk = fmaxf(maxk, kv); mink = fminf(mink, kv);
        const float qv = qrow[f]; ssq += qv * qv; maxq = fmaxf(maxq, qv); minq = fminf(minq, qv);
    }
    #pragma unroll
    for (int o = 1; o < 64; o <<= 1) {
        ssk += __shfl_xor(ssk, o, 64); ssq += __shfl_xor(ssq, o, 64);
        maxk = fmaxf(maxk, __shfl_xor(maxk, o, 64)); mink = fminf(mink, __shfl_xor(mink, o, 64));
        maxq = fmaxf(maxq, __shfl_xor(maxq, o, 64)); minq = fminf(minq, __shfl_xor(minq, o, 64));
    }
    const float qt = tq[(size_t)b * cC3 + n * 3 * cHD + h];
    const float kt = tq[(size_t)b * cC3 + n * 3 * cHD + cHD + h];
    const float sign1 = qt / fmaxf(fabsf(qt), 1e-12f);
    const float sign2 = kt / fmaxf(fabsf(kt), 1e-12f);
    const float a1 = sign1 / fmaxf(sqrtf(ssk), 1e-12f);
    const float a2 = sign2 / fmaxf(sqrtf(ssq), 1e-12f);
    const float m1 = fmaxf(a1 * maxk, a1 * mink);
    const float m2 = fmaxf(a2 * maxq, a2 * minq);
    float z1 = 0.f, z2 = 0.f;
    for (int f = lane; f < cFHW; f += 64) {
        z1 += expf(a1 * krow[f] - m1);
        z2 += expf(a2 * qrow[f] - m2);
    }
    #pragma unroll
    for (int o = 1; o < 64; o <<= 1) { z1 += __shfl_xor(z1, o, 64); z2 += __shfl_xor(z2, o, 64); }
    if (lane == 0) {
        float* sp = stats + (size_t)idx * 6;
        sp[0] = a1; sp[1] = m1; sp[2] = 1.f / z1;
        sp[3] = a2; sp[4] = m2; sp[5] = 1.f / z2;
    }
}

// ============================================================
// attention GEMM: img[b, n*192+h, g] = sum_f (P1+P2)[h,f] * v[g,f]
// ============================================================
__global__ __launch_bounds__(256) void attn_gemm_kernel(
    const float* __restrict__ qkv, const float* __restrict__ stats, float* __restrict__ img)
{
    const int h0 = blockIdx.x * 64, g0 = blockIdx.y * 64, bn = blockIdx.z;
    const int b = bn >> 2, n = bn & 3;
    __shared__ __align__(16) float Pt[16][68];
    __shared__ __align__(16) float Vt[16][68];
    __shared__ float st[6][64];
    const int tid = threadIdx.x;
    const int ty = tid >> 4, tx = tid & 15;
    if (tid < 64) {
        const float* sp = stats + ((size_t)bn * cHD + h0 + tid) * 6;
        #pragma unroll
        for (int j = 0; j < 6; j++) st[j][tid] = sp[j];
    }
    __syncthreads();
    float acc[4][4] = {};
    const size_t qbase = ((size_t)b * cC3 + n * cHD + h0) * cFHW;
    const size_t kbase = ((size_t)b * cC3 + cC + n * cHD + h0) * cFHW;
    const size_t vbase = ((size_t)b * cC3 + 2 * cC + n * cHD + g0) * cFHW;
    for (int f0 = 0; f0 < cFHW; f0 += 16) {
        const int col = tid & 15, row = tid >> 4;
        #pragma unroll
        for (int p = 0; p < 4; p++) {
            const int r = row + p * 16;
            const float kv = qkv[kbase + (size_t)r * cFHW + f0 + col];
            const float qv = qkv[qbase + (size_t)r * cFHW + f0 + col];
            Pt[col][r] = expf(st[0][r] * kv - st[1][r]) * st[2][r]
                       + expf(st[3][r] * qv - st[4][r]) * st[5][r];
            Vt[col][r] = qkv[vbase + (size_t)r * cFHW + f0 + col];
        }
        __syncthreads();
        #pragma unroll
        for (int kk = 0; kk < 16; kk++) {
            const float4 av = *(const float4*)&Pt[kk][ty * 4];
            const float4 bv = *(const float4*)&Vt[kk][tx * 4];
            acc[0][0] += av.x * bv.x; acc[0][1] += av.x * bv.y; acc[0][2] += av.x * bv.z; acc[0][3] += av.x * bv.w;
            acc[1][0] += av.y * bv.x; acc[1][1] += av.y * bv.y; acc[1][2] += av.y * bv.z; acc[1][3] += av.y * bv.w;
            acc[2][0] += av.z * bv.x; acc[2][1] += av.z * bv.y; acc[2][2] += av.z * bv.z; acc[2][3] += av.z * bv.w;
            acc[3][0] += av.w * bv.x; acc[3][1] += av.w * bv.y; acc[3][2] += av.w * bv.z; acc[3][3] += av.w * bv.w;
        }
        __syncthreads();
    }
    #pragma unroll
    for (int i = 0; i < 4; i++) {
        const size_t o = ((size_t)b * cC + n * cHD + h0 + ty * 4 + i) * cHD + g0 + tx * 4;
        *(float4*)&img[o] = make_float4(acc[i][0], acc[i][1], acc[i][2], acc[i][3]);
    }
}

// ============================================================
// y GEMM (A * B^T): y[b,m,n] = sum_k img[b,m,k]*o2w[n,k] + o2b[n]
// ============================================================
__global__ __launch_bounds__(256) void y_gemm_kernel(
    const float* __restrict__ A, const float* __restrict__ Bw,
    const float* __restrict__ bias_n, float* __restrict__ out)
{
    const int n0 = blockIdx.x * 64, m0 = blockIdx.y * 64, b = blockIdx.z;
    __shared__ __align__(16) float At[16][68];
    __shared__ __align__(16) float Bt[16][68];
    const int tid = threadIdx.x;
    const int ty = tid >> 4, tx = tid & 15;
    float acc[4][4] = {};
    for (int k0 = 0; k0 < cHD; k0 += 16) {
        const int col = tid & 15, row = tid >> 4;
        #pragma unroll
        for (int p = 0; p < 4; p++) {
            const int r = row + p * 16;
            At[col][r] = A[((size_t)b * cC + m0 + r) * cHD + k0 + col];
            Bt[col][r] = Bw[(size_t)(n0 + r) * cHD + k0 + col];
        }
        __syncthreads();
        #pragma unroll
        for (int kk = 0; kk < 16; kk++) {
            const float4 av = *(const float4*)&At[kk][ty * 4];
            const float4 bv = *(const float4*)&Bt[kk][tx * 4];
            acc[0][0] += av.x * bv.x; acc[0][1] += av.x * bv.y; acc[0][2] += av.x * bv.z; acc[0][3] += av.x * bv.w;
            acc[1][0] += av.y * bv.x; acc[1][1] += av.y * bv.y; acc[1][2] += av.y * bv.z; acc[1][3] += av.y * bv.w;
            acc[2][0] += av.z * bv.x; acc[2][1] += av.z * bv.y; acc[2][2] += av.z * bv.z; acc[2][3] += av.z * bv.w;
            acc[3][0] += av.w * bv.x; acc[3][1] += av.w * bv.y; acc[3][2] += av.w * bv.z; acc[3][3] += av.w * bv.w;
        }
        __syncthreads();
    }
    #pragma unroll
    for (int i = 0; i < 4; i++) {
        const size_t o = ((size_t)b * cC + m0 + ty * 4 + i) * cFHW + n0 + tx * 4;
        float4 v;
        v.x = acc[i][0] + bias_n[n0 + tx * 4 + 0];
        v.y = acc[i][1] + bias_n[n0 + tx * 4 + 1];
        v.z = acc[i][2] + bias_n[n0 + tx * 4 + 2];
        v.w = acc[i][3] + bias_n[n0 + tx * 4 + 3];
        *(float4*)&out[o] = v;
    }
}

// ============================================================
// depthwise 3x3 SAME + exact GELU; one block per (c,b_local); fp32
// ============================================================
__global__ __launch_bounds__(576) void dwconv_gelu_kernel(
    const float* __restrict__ X, const float* __restrict__ w, float* __restrict__ Y)
{
    const int c = blockIdx.x, b = blockIdx.y;
    __shared__ float t[26][28];
    const int tid = threadIdx.x;
    float* tf = &t[0][0];
    for (int i = tid; i < 26 * 28; i += 576) tf[i] = 0.f;
    __syncthreads();
    const size_t base = ((size_t)b * cC + c) * cFHW;
    const int x = tid % 24, y = tid / 24;
    t[y + 1][x + 1] = X[base + tid];
    __syncthreads();
    float w9[9];
    #pragma unroll
    for (int j = 0; j < 9; j++) w9[j] = w[c * 9 + j];
    float s = 0.f;
    #pragma unroll
    for (int dy = 0; dy < 3; dy++)
        #pragma unroll
        for (int dx = 0; dx < 3; dx++)
            s += w9[dy * 3 + dx] * t[y + dy][x + dx];
    const float g = 0.5f * s * (1.f + erff(s * 0.70710678118654752f));
    Y[base + tid] = g;
}

// ============================================================
extern "C" void kernel_launch(void* const* d_in, const int* in_sizes, int n_in,
                              void* d_out, int out_size, void* d_ws, size_t ws_size,
                              hipStream_t stream)
{
    const size_t QCF = (size_t)cQ * cC * cFHW;   // 3,538,944 elems per quarter slot

    // ---- workspace layout (fp32, 256B-aligned); peak ~82 MB ----
    char* p = (char*)d_ws;
    auto alloc = [&](size_t elems) { char* r = p; p += (elems * 4 + 255) & ~(size_t)255; return (float*)r; };
    float* c_txt   = alloc((size_t)cB * cD);
    float* c_fnw   = alloc(cC);
    float* c_fnb   = alloc(cC);
    float* c_gnw   = alloc(cD);
    float* c_gnb   = alloc(cD);
    float* c_qkviw = alloc((size_t)cC3 * cC);
    float* c_qkvtw = alloc((size_t)cC3 * cD);
    float* c_oiw   = alloc((size_t)cC * cC);
    float* c_oib   = alloc(cC);
    float* c_oi2w  = alloc((size_t)cFHW * cHD);
    float* c_oi2b  = alloc(cFHW);
    float* c_ffnw  = alloc(cC);
    float* c_ffnb  = alloc(cC);
    float* c_fc1   = alloc((size_t)cC * cC);
    float* c_dw    = alloc(cC * 9);
    float* c_fc2   = alloc((size_t)cC * cC);
    int*   flags   = (int*)alloc(64);
    float* tq      = alloc((size_t)cB * cC3);
    float* stats   = alloc((size_t)cQ * cNH * cHD * 6);
    float* slotB   = alloc(QCF);          // xq / ybq
    float* slotA   = alloc(3 * QCF);      // qkvq; then outq=A0, zaq=A1, zbq=A2, zgq=A1
    float* slotC   = alloc((size_t)cQ * cC * cHD);   // imgq
    float* A0 = slotA, *A1 = slotA + QCF, *A2 = slotA + 2 * QCF;
    (void)ws_size; (void)in_sizes; (void)n_in; (void)out_size;

    // ---- dtype probe + canonicalize inputs (all but img_feats) to fp32 ----
    detect_kernel<<<1, 1, 0, stream>>>((const u16*)d_in[2], flags);
    struct CV { const void* src; float* dst; int n; };
    const CV cv[16] = {
        { d_in[1],  c_txt,   cB * cD },
        { d_in[2],  c_fnw,   cC },
        { d_in[3],  c_fnb,   cC },
        { d_in[4],  c_gnw,   cD },
        { d_in[5],  c_gnb,   cD },
        { d_in[6],  c_qkviw, cC3 * cC },
        { d_in[7],  c_qkvtw, cC3 * cD },
        { d_in[8],  c_oiw,   cC * cC },
        { d_in[9],  c_oib,   cC },
        { d_in[10], c_oi2w,  cFHW * cHD },
        { d_in[11], c_oi2b,  cFHW },
        { d_in[12], c_ffnw,  cC },
        { d_in[13], c_ffnb,  cC },
        { d_in[14], c_fc1,   cC * cC },
        { d_in[15], c_dw,    cC * 9 },
        { d_in[16], c_fc2,   cC * cC },
    };
    for (int i = 0; i < 16; i++)
        conv_in_kernel<<<(cv[i].n + 255) / 256, 256, 0, stream>>>(cv[i].src, cv[i].dst, cv[i].n, flags);

    txt_qkv_kernel<<<cB, 256, 0, stream>>>(c_txt, c_gnw, c_gnb, c_qkvtw, tq);

    // ---- per-quarter pipeline (batch elements are fully independent) ----
    for (int q = 0; q < 4; q++) {
        const int b0 = q * cQ;
        const size_t off = (size_t)b0 * cC * cFHW;   // element offset into (B,C,F)
        ln2d_kernel<1><<<dim3(9, cQ), 256, 0, stream>>>(d_in[0], off, c_fnw, c_fnb, slotB, flags);
        conv_gemm<0><<<dim3(9, 36, cQ), 256, 0, stream>>>(c_qkviw, slotB, slotA,
                                                          nullptr, nullptr, 0, nullptr, cC3, cC, flags);
        attn_stats_kernel<<<cQ * cNH * cHD, 64, 0, stream>>>(slotA, tq + (size_t)b0 * cC3, stats);
        attn_gemm_kernel<<<dim3(3, 3, cQ * cNH), 256, 0, stream>>>(slotA, stats, slotC);
        y_gemm_kernel<<<dim3(9, 12, cQ), 256, 0, stream>>>(slotC, c_oi2w, c_oi2b, slotB);
        conv_gemm<1><<<dim3(9, 12, cQ), 256, 0, stream>>>(c_oiw, slotB, A0,
                                                          c_oib, d_in[0], off, nullptr, cC, cC, flags);
        ln2d_kernel<0><<<dim3(9, cQ), 256, 0, stream>>>(A0, 0, c_ffnw, c_ffnb, A1, flags);
        conv_gemm<0><<<dim3(9, 12, cQ), 256, 0, stream>>>(c_fc1, A1, A2,
                                                          nullptr, nullptr, 0, nullptr, cC, cC, flags);
        dwconv_gelu_kernel<<<dim3(cC, cQ), 576, 0, stream>>>(A2, c_dw, A1);
        conv_gemm<2><<<dim3(9, 12, cQ), 256, 0, stream>>>(c_fc2, A1, (float*)d_out + off,
                                                          nullptr, nullptr, 0, A0, cC, cC, flags);
    }
}

// Round 6
// 3870.691 us; speedup vs baseline: 1.0150x; 1.0150x over previous
//
#include <hip/hip_runtime.h>

typedef unsigned short u16;

// ---- problem constants ----
static constexpr int cB   = 32;
static constexpr int cC   = 768;
static constexpr int cD   = 512;
static constexpr int cNH  = 4;
static constexpr int cHD  = 192;   // C/NH
static constexpr int cFHW = 576;   // 24*24
static constexpr int cC3  = 2304;  // 3*C
static constexpr int cQ   = 8;     // quarter-batch

__device__ inline float us2f(u16 s) {
    union { unsigned int u; float f; } v; v.u = ((unsigned int)s) << 16; return v.f;
}
// flag-dispatched load from a raw d_in pointer: bf16 (flag 0) or fp32 (flag 1)
__device__ inline float ldflex(const void* p, size_t i, int isf32) {
    return isf32 ? ((const float*)p)[i] : us2f(((const u16*)p)[i]);
}

// dtype probe: fp32 ones -> u16[0]=0x0000 (low mantissa half); bf16 ones -> 0x3F80.
__global__ void detect_kernel(const u16* __restrict__ raw, int* __restrict__ flags) {
    flags[0] = (raw[0] == 0x3F80u) ? 0 : 1;
}

// ---- one-shot canonicalization of 12 small arrays to fp32 ----
struct FlatDesc { const void* src[12]; float* dst[12]; int off[13]; };
__global__ __launch_bounds__(256) void flatten_kernel(FlatDesc d, const int* __restrict__ flags) {
    const int isf = flags[0];
    const int gid = blockIdx.x * 256 + threadIdx.x;
    if (gid >= d.off[12]) return;
    int s = 0;
    #pragma unroll
    for (int i = 1; i < 12; i++) s += (gid >= d.off[i]) ? 1 : 0;
    const int j = gid - d.off[s];
    d.dst[s][j] = ldflex(d.src[s], j, isf);
}

// ---- tiled transpose: dst[k][m] = src[m][k], dims multiple of 32 ----
__global__ __launch_bounds__(256) void transpose_kernel(
    const void* __restrict__ src, float* __restrict__ dst,
    int Mdim, int Kdim, const int* __restrict__ flags)
{
    __shared__ float t[32][33];
    const int isf = flags[0];
    const int k0 = blockIdx.x * 32, m0 = blockIdx.y * 32;
    const int x = threadIdx.x & 31, y = threadIdx.x >> 5;   // 32 x 8
    #pragma unroll
    for (int i = 0; i < 4; i++) {
        const int m = y + i * 8;
        t[m][x] = ldflex(src, (size_t)(m0 + m) * Kdim + k0 + x, isf);
    }
    __syncthreads();
    #pragma unroll
    for (int i = 0; i < 4; i++) {
        const int r = y + i * 8;
        dst[(size_t)(k0 + r) * Mdim + m0 + x] = t[x][r];
    }
}

// ============================================================
// txt LN (eps 1e-5) + qkv_txt GEMM: (B,512) -> (B,2304) fp32
// ============================================================
__global__ __launch_bounds__(256) void txt_qkv_kernel(
    const float* __restrict__ txt, const float* __restrict__ gw, const float* __restrict__ gb,
    const float* __restrict__ W, float* __restrict__ out)
{
    __shared__ float tln[cD];
    __shared__ float red[8];
    const int b = blockIdx.x, tid = threadIdx.x;
    const float v0 = txt[(size_t)b * cD + tid];
    const float v1 = txt[(size_t)b * cD + 256 + tid];
    float s = v0 + v1, ss = v0 * v0 + v1 * v1;
    #pragma unroll
    for (int o = 1; o < 64; o <<= 1) { s += __shfl_xor(s, o, 64); ss += __shfl_xor(ss, o, 64); }
    const int wid = tid >> 6, lane = tid & 63;
    if (lane == 0) { red[wid] = s; red[4 + wid] = ss; }
    __syncthreads();
    s  = red[0] + red[1] + red[2] + red[3];
    ss = red[4] + red[5] + red[6] + red[7];
    const float mean = s * (1.f / cD);
    const float var  = fmaxf(ss * (1.f / cD) - mean * mean, 0.f);
    const float r = rsqrtf(var + 1e-5f);
    tln[tid]       = (v0 - mean) * r * gw[tid]       + gb[tid];
    tln[tid + 256] = (v1 - mean) * r * gw[tid + 256] + gb[tid + 256];
    __syncthreads();
    #pragma unroll 1
    for (int j = 0; j < 9; j++) {
        const int o = tid + j * 256;
        const float4* wr = (const float4*)(W + (size_t)o * cD);
        float acc = 0.f;
        #pragma unroll 4
        for (int d4 = 0; d4 < cD / 4; d4++) {
            const float4 wv = wr[d4];
            const float* tp = &tln[d4 * 4];
            acc += tp[0] * wv.x + tp[1] * wv.y + tp[2] * wv.z + tp[3] * wv.w;
        }
        out[(size_t)b * cC3 + o] = acc;
    }
}

// ============================================================
// channel LayerNorm over C (eps 1e-6), fp32 out.
// RAW=1: x is raw d_in (flag dtype), xoff = b0*C*FHW element offset.
// ============================================================
template <int RAW>
__global__ __launch_bounds__(256) void ln2d_kernel(
    const void* __restrict__ x, size_t xoff, const float* __restrict__ w,
    const float* __restrict__ bias, float* __restrict__ out, const int* __restrict__ flags)
{
    const int isf = RAW ? flags[0] : 1;
    const int b = blockIdx.y;
    const int l = threadIdx.x & 63;
    const int f = (blockIdx.x << 6) + l;
    const int c4 = threadIdx.x >> 6;
    const size_t base = (size_t)b * cC * cFHW + f;
    const size_t rbase = RAW ? (xoff + base) : base;
    float s = 0.f, ss = 0.f;
    for (int c = c4; c < cC; c += 4) {
        float v = RAW ? ldflex(x, rbase + (size_t)c * cFHW, isf)
                      : ((const float*)x)[base + (size_t)c * cFHW];
        s += v; ss += v * v;
    }
    __shared__ float S[4][64], SS[4][64];
    S[c4][l] = s; SS[c4][l] = ss;
    __syncthreads();
    const float sum  = S[0][l] + S[1][l] + S[2][l] + S[3][l];
    const float ssum = SS[0][l] + SS[1][l] + SS[2][l] + SS[3][l];
    const float mean = sum * (1.f / cC);
    const float var  = fmaxf(ssum * (1.f / cC) - mean * mean, 0.f);
    const float r = rsqrtf(var + 1e-6f);
    for (int c = c4; c < cC; c += 4) {
        float v = RAW ? ldflex(x, rbase + (size_t)c * cFHW, isf)
                      : ((const float*)x)[base + (size_t)c * cFHW];
        out[base + (size_t)c * cFHW] = w[c] * ((v - mean) * r) + bias[c];
    }
}

// ============================================================
// 1x1-conv GEMM: out[b,m,n] = sum_k Wt[k,m] * X[b,k,n]   (N=576)
// Wt is K x M (pre-transposed). 128x128 tile (n-edge 64), 256 thr,
// 8x8 micro: rows m0+ty*8+i, cols {n0+tx*4+j, n0+64+tx*4+j}.
// EPI 0: f32 out = acc
// EPI 1: f32 out = acc + bias_m + resRaw[resOff+o] (flag dtype)
// EPI 2: f32 out = acc + resF[o]   (writes d_out)
// ============================================================
template <int EPI>
__global__ __launch_bounds__(256) void conv_gemm(
    const float* __restrict__ Wt, const float* __restrict__ X, float* __restrict__ outp,
    const float* __restrict__ bias_m, const void* __restrict__ resRaw, size_t resOff,
    const float* __restrict__ resF, int M, int K, const int* __restrict__ flags)
{
    const int n0 = blockIdx.x * 128, m0 = blockIdx.y * 128, b = blockIdx.z;
    __shared__ __align__(16) float At[16][132];   // At[k][m]
    __shared__ __align__(16) float Bt[16][132];   // Bt[k][n]
    const int tid = threadIdx.x;
    const int tx = tid & 15, ty = tid >> 4;
    const bool g1 = (n0 + 127) < cFHW;            // second col-group valid (block-uniform)
    const int nmax = cFHW - n0;
    float acc[8][8] = {};
    const size_t xbase = (size_t)b * K * cFHW;
    for (int k0 = 0; k0 < K; k0 += 16) {
        #pragma unroll
        for (int i = 0; i < 2; i++) {
            const int idx = tid + i * 256;
            const int kl = idx >> 5, mq = idx & 31;
            const float4 av = *(const float4*)(Wt + (size_t)(k0 + kl) * M + m0 + mq * 4);
            *(float4*)&At[kl][mq * 4] = av;
            float4 bv = make_float4(0.f, 0.f, 0.f, 0.f);
            if (mq * 4 < nmax)
                bv = *(const float4*)(X + xbase + (size_t)(k0 + kl) * cFHW + n0 + mq * 4);
            *(float4*)&Bt[kl][mq * 4] = bv;
        }
        __syncthreads();
        #pragma unroll
        for (int kk = 0; kk < 16; kk++) {
            float a[8], bb[8];
            *(float4*)&a[0]  = *(const float4*)&At[kk][ty * 8];
            *(float4*)&a[4]  = *(const float4*)&At[kk][ty * 8 + 4];
            *(float4*)&bb[0] = *(const float4*)&Bt[kk][tx * 4];
            *(float4*)&bb[4] = *(const float4*)&Bt[kk][64 + tx * 4];
            #pragma unroll
            for (int i = 0; i < 8; i++)
                #pragma unroll
                for (int j = 0; j < 8; j++)
                    acc[i][j] += a[i] * bb[j];
        }
        __syncthreads();
    }
    const int isf = (EPI == 1) ? flags[0] : 1;
    #pragma unroll
    for (int i = 0; i < 8; i++) {
        const int m = m0 + ty * 8 + i;
        const size_t rowo = ((size_t)b * M + m) * cFHW;
        #pragma unroll
        for (int g = 0; g < 2; g++) {
            if (g == 1 && !g1) continue;
            const int cb = n0 + g * 64 + tx * 4;
            const size_t o = rowo + cb;
            float4 v = make_float4(acc[i][g*4+0], acc[i][g*4+1], acc[i][g*4+2], acc[i][g*4+3]);
            if constexpr (EPI == 1) {
                const float bm = bias_m[m];
                v.x += bm + ldflex(resRaw, resOff + o + 0, isf);
                v.y += bm + ldflex(resRaw, resOff + o + 1, isf);
                v.z += bm + ldflex(resRaw, resOff + o + 2, isf);
                v.w += bm + ldflex(resRaw, resOff + o + 3, isf);
            } else if constexpr (EPI == 2) {
                const float4 rv = *(const float4*)&resF[o];
                v.x += rv.x; v.y += rv.y; v.z += rv.z; v.w += rv.w;
            }
            *(float4*)&outp[o] = v;
        }
    }
}

// ============================================================
// attention stats: per (b_local,n,h) -> a1,m1,1/Z1,a2,m2,1/Z2
// ============================================================
__global__ __launch_bounds__(64) void attn_stats_kernel(
    const float* __restrict__ qkv, const float* __restrict__ tq, float* __restrict__ stats)
{
    const int idx = blockIdx.x;
    const int h = idx % cHD;
    const int bn = idx / cHD;
    const int n = bn & 3, b = bn >> 2;
    const int lane = threadIdx.x;
    const float* qrow = qkv + ((size_t)b * cC3 + n * cHD + h) * cFHW;
    const float* krow = qkv + ((size_t)b * cC3 + cC + n * cHD + h) * cFHW;
    float ssk = 0.f, mink = 3.0e38f, maxk = -3.0e38f;
    float ssq = 0.f, minq = 3.0e38f, maxq = -3.0e38f;
    for (int f = lane; f < cFHW; f += 64) {
        const float kv = krow[f]; ssk += kv * kv; maxk = fmaxf(maxk, kv); mink = fminf(mink, kv);
        const float qv = qrow[f]; ssq += qv * qv; maxq = fmaxf(maxq, qv); minq = fminf(minq, qv);
    }
    #pragma unroll
    for (int o = 1; o < 64; o <<= 1) {
        ssk += __shfl_xor(ssk, o, 64); ssq += __shfl_xor(ssq, o, 64);
        maxk = fmaxf(maxk, __shfl_xor(maxk, o, 64)); mink = fminf(mink, __shfl_xor(mink, o, 64));
        maxq = fmaxf(maxq, __shfl_xor(maxq, o, 64)); minq = fminf(minq, __shfl_xor(minq, o, 64));
    }
    const float qt = tq[(size_t)b * cC3 + n * 3 * cHD + h];
    const float kt = tq[(size_t)b * cC3 + n * 3 * cHD + cHD + h];
    const float sign1 = qt / fmaxf(fabsf(qt), 1e-12f);
    const float sign2 = kt / fmaxf(fabsf(kt), 1e-12f);
    const float a1 = sign1 / fmaxf(sqrtf(ssk), 1e-12f);
    const float a2 = sign2 / fmaxf(sqrtf(ssq), 1e-12f);
    const float m1 = fmaxf(a1 * maxk, a1 * mink);
    const float m2 = fmaxf(a2 * maxq, a2 * minq);
    float z1 = 0.f, z2 = 0.f;
    for (int f = lane; f < cFHW; f += 64) {
        z1 += expf(a1 * krow[f] - m1);
        z2 += expf(a2 * qrow[f] - m2);
    }
    #pragma unroll
    for (int o = 1; o < 64; o <<= 1) { z1 += __shfl_xor(z1, o, 64); z2 += __shfl_xor(z2, o, 64); }
    if (lane == 0) {
        float* sp = stats + (size_t)idx * 6;
        sp[0] = a1; sp[1] = m1; sp[2] = 1.f / z1;
        sp[3] = a2; sp[4] = m2; sp[5] = 1.f / z2;
    }
}

// ============================================================
// attention GEMM: img[b, n*192+h, g] = sum_f (P1+P2)[h,f] * v[g,f]
// ============================================================
__global__ __launch_bounds__(256) void attn_gemm_kernel(
    const float* __restrict__ qkv, const float* __restrict__ stats, float* __restrict__ img)
{
    const int h0 = blockIdx.x * 64, g0 = blockIdx.y * 64, bn = blockIdx.z;
    const int b = bn >> 2, n = bn & 3;
    __shared__ __align__(16) float Pt[16][68];
    __shared__ __align__(16) float Vt[16][68];
    __shared__ float st[6][64];
    const int tid = threadIdx.x;
    const int ty = tid >> 4, tx = tid & 15;
    if (tid < 64) {
        const float* sp = stats + ((size_t)bn * cHD + h0 + tid) * 6;
        #pragma unroll
        for (int j = 0; j < 6; j++) st[j][tid] = sp[j];
    }
    __syncthreads();
    float acc[4][4] = {};
    const size_t qbase = ((size_t)b * cC3 + n * cHD + h0) * cFHW;
    const size_t kbase = ((size_t)b * cC3 + cC + n * cHD + h0) * cFHW;
    const size_t vbase = ((size_t)b * cC3 + 2 * cC + n * cHD + g0) * cFHW;
    for (int f0 = 0; f0 < cFHW; f0 += 16) {
        const int col = tid & 15, row = tid >> 4;
        #pragma unroll
        for (int p = 0; p < 4; p++) {
            const int r = row + p * 16;
            const float kv = qkv[kbase + (size_t)r * cFHW + f0 + col];
            const float qv = qkv[qbase + (size_t)r * cFHW + f0 + col];
            Pt[col][r] = expf(st[0][r] * kv - st[1][r]) * st[2][r]
                       + expf(st[3][r] * qv - st[4][r]) * st[5][r];
            Vt[col][r] = qkv[vbase + (size_t)r * cFHW + f0 + col];
        }
        __syncthreads();
        #pragma unroll
        for (int kk = 0; kk < 16; kk++) {
            const float4 av = *(const float4*)&Pt[kk][ty * 4];
            const float4 bv = *(const float4*)&Vt[kk][tx * 4];
            acc[0][0] += av.x * bv.x; acc[0][1] += av.x * bv.y; acc[0][2] += av.x * bv.z; acc[0][3] += av.x * bv.w;
            acc[1][0] += av.y * bv.x; acc[1][1] += av.y * bv.y; acc[1][2] += av.y * bv.z; acc[1][3] += av.y * bv.w;
            acc[2][0] += av.z * bv.x; acc[2][1] += av.z * bv.y; acc[2][2] += av.z * bv.z; acc[2][3] += av.z * bv.w;
            acc[3][0] += av.w * bv.x; acc[3][1] += av.w * bv.y; acc[3][2] += av.w * bv.z; acc[3][3] += av.w * bv.w;
        }
        __syncthreads();
    }
    #pragma unroll
    for (int i = 0; i < 4; i++) {
        const size_t o = ((size_t)b * cC + n * cHD + h0 + ty * 4 + i) * cHD + g0 + tx * 4;
        *(float4*)&img[o] = make_float4(acc[i][0], acc[i][1], acc[i][2], acc[i][3]);
    }
}

// ============================================================
// y GEMM (A * B^T): y[b,m,n] = sum_k img[b,m,k]*o2w[n,k] + o2b[n]
// ============================================================
__global__ __launch_bounds__(256) void y_gemm_kernel(
    const float* __restrict__ A, const float* __restrict__ Bw,
    const float* __restrict__ bias_n, float* __restrict__ out)
{
    const int n0 = blockIdx.x * 64, m0 = blockIdx.y * 64, b = blockIdx.z;
    __shared__ __align__(16) float At[16][68];
    __shared__ __align__(16) float Bt[16][68];
    const int tid = threadIdx.x;
    const int ty = tid >> 4, tx = tid & 15;
    float acc[4][4] = {};
    for (int k0 = 0; k0 < cHD; k0 += 16) {
        const int col = tid & 15, row = tid >> 4;
        #pragma unroll
        for (int p = 0; p < 4; p++) {
            const int r = row + p * 16;
            At[col][r] = A[((size_t)b * cC + m0 + r) * cHD + k0 + col];
            Bt[col][r] = Bw[(size_t)(n0 + r) * cHD + k0 + col];
        }
        __syncthreads();
        #pragma unroll
        for (int kk = 0; kk < 16; kk++) {
            const float4 av = *(const float4*)&At[kk][ty * 4];
            const float4 bv = *(const float4*)&Bt[kk][tx * 4];
            acc[0][0] += av.x * bv.x; acc[0][1] += av.x * bv.y; acc[0][2] += av.x * bv.z; acc[0][3] += av.x * bv.w;
            acc[1][0] += av.y * bv.x; acc[1][1] += av.y * bv.y; acc[1][2] += av.y * bv.z; acc[1][3] += av.y * bv.w;
            acc[2][0] += av.z * bv.x; acc[2][1] += av.z * bv.y; acc[2][2] += av.z * bv.z; acc[2][3] += av.z * bv.w;
            acc[3][0] += av.w * bv.x; acc[3][1] += av.w * bv.y; acc[3][2] += av.w * bv.z; acc[3][3] += av.w * bv.w;
        }
        __syncthreads();
    }
    #pragma unroll
    for (int i = 0; i < 4; i++) {
        const size_t o = ((size_t)b * cC + m0 + ty * 4 + i) * cFHW + n0 + tx * 4;
        float4 v;
        v.x = acc[i][0] + bias_n[n0 + tx * 4 + 0];
        v.y = acc[i][1] + bias_n[n0 + tx * 4 + 1];
        v.z = acc[i][2] + bias_n[n0 + tx * 4 + 2];
        v.w = acc[i][3] + bias_n[n0 + tx * 4 + 3];
        *(float4*)&out[o] = v;
    }
}

// ============================================================
// depthwise 3x3 SAME + exact GELU; one block per (c,b_local); fp32
// ============================================================
__global__ __launch_bounds__(576) void dwconv_gelu_kernel(
    const float* __restrict__ X, const float* __restrict__ w, float* __restrict__ Y)
{
    const int c = blockIdx.x, b = blockIdx.y;
    __shared__ float t[26][28];
    const int tid = threadIdx.x;
    float* tf = &t[0][0];
    for (int i = tid; i < 26 * 28; i += 576) tf[i] = 0.f;
    __syncthreads();
    const size_t base = ((size_t)b * cC + c) * cFHW;
    const int x = tid % 24, y = tid / 24;
    t[y + 1][x + 1] = X[base + tid];
    __syncthreads();
    float w9[9];
    #pragma unroll
    for (int j = 0; j < 9; j++) w9[j] = w[c * 9 + j];
    float s = 0.f;
    #pragma unroll
    for (int dy = 0; dy < 3; dy++)
        #pragma unroll
        for (int dx = 0; dx < 3; dx++)
            s += w9[dy * 3 + dx] * t[y + dy][x + dx];
    const float g = 0.5f * s * (1.f + erff(s * 0.70710678118654752f));
    Y[base + tid] = g;
}

// ============================================================
extern "C" void kernel_launch(void* const* d_in, const int* in_sizes, int n_in,
                              void* d_out, int out_size, void* d_ws, size_t ws_size,
                              hipStream_t stream)
{
    const size_t QCF = (size_t)cQ * cC * cFHW;   // 3,538,944 elems per quarter slot

    // ---- workspace layout (fp32, 256B-aligned); peak ~82 MB ----
    char* p = (char*)d_ws;
    auto alloc = [&](size_t elems) { char* r = p; p += (elems * 4 + 255) & ~(size_t)255; return (float*)r; };
    float* c_txt   = alloc((size_t)cB * cD);
    float* c_fnw   = alloc(cC);
    float* c_fnb   = alloc(cC);
    float* c_gnw   = alloc(cD);
    float* c_gnb   = alloc(cD);
    float* t_qkvw  = alloc((size_t)cC3 * cC);    // transposed K x M
    float* c_qkvtw = alloc((size_t)cC3 * cD);
    float* t_oiw   = alloc((size_t)cC * cC);     // transposed
    float* c_oib   = alloc(cC);
    float* c_oi2w  = alloc((size_t)cFHW * cHD);
    float* c_oi2b  = alloc(cFHW);
    float* c_ffnw  = alloc(cC);
    float* c_ffnb  = alloc(cC);
    float* t_fc1   = alloc((size_t)cC * cC);     // transposed
    float* c_dw    = alloc(cC * 9);
    float* t_fc2   = alloc((size_t)cC * cC);     // transposed
    int*   flags   = (int*)alloc(64);
    float* tq      = alloc((size_t)cB * cC3);
    float* stats   = alloc((size_t)cQ * cNH * cHD * 6);
    float* slotB   = alloc(QCF);          // xq / ybq
    float* slotA   = alloc(3 * QCF);      // qkvq; then outq=A0, zaq=A1, zbq=A2, zgq=A1
    float* slotC   = alloc((size_t)cQ * cC * cHD);   // imgq
    float* A0 = slotA, *A1 = slotA + QCF, *A2 = slotA + 2 * QCF;
    (void)ws_size; (void)in_sizes; (void)n_in; (void)out_size;

    // ---- dtype probe ----
    detect_kernel<<<1, 1, 0, stream>>>((const u16*)d_in[2], flags);

    // ---- canonicalize 12 small arrays in one launch ----
    FlatDesc fd;
    const void* srcs[12] = { d_in[1], d_in[2], d_in[3], d_in[4], d_in[5], d_in[7],
                             d_in[9], d_in[10], d_in[11], d_in[12], d_in[13], d_in[15] };
    float* dsts[12]      = { c_txt, c_fnw, c_fnb, c_gnw, c_gnb, c_qkvtw,
                             c_oib, c_oi2w, c_oi2b, c_ffnw, c_ffnb, c_dw };
    const int ns[12]     = { cB * cD, cC, cC, cD, cD, cC3 * cD,
                             cC, cFHW * cHD, cFHW, cC, cC, cC * 9 };
    int tot = 0;
    for (int i = 0; i < 12; i++) { fd.src[i] = srcs[i]; fd.dst[i] = dsts[i]; fd.off[i] = tot; tot += ns[i]; }
    fd.off[12] = tot;
    flatten_kernel<<<(tot + 255) / 256, 256, 0, stream>>>(fd, flags);

    // ---- transpose the 4 big weights (Wt[k][m] = W[m][k]) ----
    transpose_kernel<<<dim3(cC / 32, cC3 / 32), 256, 0, stream>>>(d_in[6],  t_qkvw, cC3, cC, flags);
    transpose_kernel<<<dim3(cC / 32, cC / 32),  256, 0, stream>>>(d_in[8],  t_oiw,  cC,  cC, flags);
    transpose_kernel<<<dim3(cC / 32, cC / 32),  256, 0, stream>>>(d_in[14], t_fc1,  cC,  cC, flags);
    transpose_kernel<<<dim3(cC / 32, cC / 32),  256, 0, stream>>>(d_in[16], t_fc2,  cC,  cC, flags);

    txt_qkv_kernel<<<cB, 256, 0, stream>>>(c_txt, c_gnw, c_gnb, c_qkvtw, tq);

    // ---- per-quarter pipeline (batch elements are fully independent) ----
    for (int q = 0; q < 4; q++) {
        const int b0 = q * cQ;
        const size_t off = (size_t)b0 * cC * cFHW;   // element offset into (B,C,F)
        ln2d_kernel<1><<<dim3(9, cQ), 256, 0, stream>>>(d_in[0], off, c_fnw, c_fnb, slotB, flags);
        conv_gemm<0><<<dim3(5, 18, cQ), 256, 0, stream>>>(t_qkvw, slotB, slotA,
                                                          nullptr, nullptr, 0, nullptr, cC3, cC, flags);
        attn_stats_kernel<<<cQ * cNH * cHD, 64, 0, stream>>>(slotA, tq + (size_t)b0 * cC3, stats);
        attn_gemm_kernel<<<dim3(3, 3, cQ * cNH), 256, 0, stream>>>(slotA, stats, slotC);
        y_gemm_kernel<<<dim3(9, 12, cQ), 256, 0, stream>>>(slotC, c_oi2w, c_oi2b, slotB);
        conv_gemm<1><<<dim3(5, 6, cQ), 256, 0, stream>>>(t_oiw, slotB, A0,
                                                         c_oib, d_in[0], off, nullptr, cC, cC, flags);
        ln2d_kernel<0><<<dim3(9, cQ), 256, 0, stream>>>(A0, 0, c_ffnw, c_ffnb, A1, flags);
        conv_gemm<0><<<dim3(5, 6, cQ), 256, 0, stream>>>(t_fc1, A1, A2,
                                                         nullptr, nullptr, 0, nullptr, cC, cC, flags);
        dwconv_gelu_kernel<<<dim3(cC, cQ), 576, 0, stream>>>(A2, c_dw, A1);
        conv_gemm<2><<<dim3(5, 6, cQ), 256, 0, stream>>>(t_fc2, A1, (float*)d_out + off,
                                                         nullptr, nullptr, 0, A0, cC, cC, flags);
    }
}

// Round 7
// 2443.377 us; speedup vs baseline: 1.6080x; 1.5842x over previous
//
#include <hip/hip_runtime.h>

typedef unsigned short u16;

// ---- problem constants ----
static constexpr int cB   = 32;
static constexpr int cC   = 768;
static constexpr int cD   = 512;
static constexpr int cNH  = 4;
static constexpr int cHD  = 192;   // C/NH
static constexpr int cFHW = 576;   // 24*24
static constexpr int cC3  = 2304;  // 3*C

__device__ inline float us2f(u16 s) {
    union { unsigned int u; float f; } v; v.u = ((unsigned int)s) << 16; return v.f;
}
// flag-dispatched load from a raw d_in pointer: bf16 (flag 0) or fp32 (flag 1)
__device__ inline float ldflex(const void* p, size_t i, int isf32) {
    return isf32 ? ((const float*)p)[i] : us2f(((const u16*)p)[i]);
}

// dtype probe: fp32 ones -> u16[0]=0x0000 (low mantissa half); bf16 ones -> 0x3F80.
__global__ void detect_kernel(const u16* __restrict__ raw, int* __restrict__ flags) {
    flags[0] = (raw[0] == 0x3F80u) ? 0 : 1;
}

// ---- one-shot canonicalization of 12 small arrays to fp32 ----
struct FlatDesc { const void* src[12]; float* dst[12]; int off[13]; };
__global__ __launch_bounds__(256) void flatten_kernel(FlatDesc d, const int* __restrict__ flags) {
    const int isf = flags[0];
    const int gid = blockIdx.x * 256 + threadIdx.x;
    if (gid >= d.off[12]) return;
    int s = 0;
    #pragma unroll
    for (int i = 1; i < 12; i++) s += (gid >= d.off[i]) ? 1 : 0;
    const int j = gid - d.off[s];
    d.dst[s][j] = ldflex(d.src[s], j, isf);
}

// ---- tiled transpose: dst[k][m] = src[m][k], dims multiple of 32 ----
__global__ __launch_bounds__(256) void transpose_kernel(
    const void* __restrict__ src, float* __restrict__ dst,
    int Mdim, int Kdim, const int* __restrict__ flags)
{
    __shared__ float t[32][33];
    const int isf = flags[0];
    const int k0 = blockIdx.x * 32, m0 = blockIdx.y * 32;
    const int x = threadIdx.x & 31, y = threadIdx.x >> 5;   // 32 x 8
    #pragma unroll
    for (int i = 0; i < 4; i++) {
        const int m = y + i * 8;
        t[m][x] = ldflex(src, (size_t)(m0 + m) * Kdim + k0 + x, isf);
    }
    __syncthreads();
    #pragma unroll
    for (int i = 0; i < 4; i++) {
        const int r = y + i * 8;
        dst[(size_t)(k0 + r) * Mdim + m0 + x] = t[x][r];
    }
}

// ============================================================
// txt LN (eps 1e-5) + qkv_txt GEMM: (B,512) -> (B,2304) fp32
// ============================================================
__global__ __launch_bounds__(256) void txt_qkv_kernel(
    const float* __restrict__ txt, const float* __restrict__ gw, const float* __restrict__ gb,
    const float* __restrict__ W, float* __restrict__ out)
{
    __shared__ float tln[cD];
    __shared__ float red[8];
    const int b = blockIdx.x, tid = threadIdx.x;
    const float v0 = txt[(size_t)b * cD + tid];
    const float v1 = txt[(size_t)b * cD + 256 + tid];
    float s = v0 + v1, ss = v0 * v0 + v1 * v1;
    #pragma unroll
    for (int o = 1; o < 64; o <<= 1) { s += __shfl_xor(s, o, 64); ss += __shfl_xor(ss, o, 64); }
    const int wid = tid >> 6, lane = tid & 63;
    if (lane == 0) { red[wid] = s; red[4 + wid] = ss; }
    __syncthreads();
    s  = red[0] + red[1] + red[2] + red[3];
    ss = red[4] + red[5] + red[6] + red[7];
    const float mean = s * (1.f / cD);
    const float var  = fmaxf(ss * (1.f / cD) - mean * mean, 0.f);
    const float r = rsqrtf(var + 1e-5f);
    tln[tid]       = (v0 - mean) * r * gw[tid]       + gb[tid];
    tln[tid + 256] = (v1 - mean) * r * gw[tid + 256] + gb[tid + 256];
    __syncthreads();
    #pragma unroll 1
    for (int j = 0; j < 9; j++) {
        const int o = tid + j * 256;
        const float4* wr = (const float4*)(W + (size_t)o * cD);
        float acc = 0.f;
        #pragma unroll 4
        for (int d4 = 0; d4 < cD / 4; d4++) {
            const float4 wv = wr[d4];
            const float* tp = &tln[d4 * 4];
            acc += tp[0] * wv.x + tp[1] * wv.y + tp[2] * wv.z + tp[3] * wv.w;
        }
        out[(size_t)b * cC3 + o] = acc;
    }
}

// ============================================================
// channel LayerNorm over C (eps 1e-6), fp32 out.
// RAW=1: x is raw d_in (flag dtype), xoff = b0*C*FHW element offset.
// ============================================================
template <int RAW>
__global__ __launch_bounds__(256) void ln2d_kernel(
    const void* __restrict__ x, size_t xoff, const float* __restrict__ w,
    const float* __restrict__ bias, float* __restrict__ out, const int* __restrict__ flags)
{
    const int isf = RAW ? flags[0] : 1;
    const int b = blockIdx.y;
    const int l = threadIdx.x & 63;
    const int f = (blockIdx.x << 6) + l;
    const int c4 = threadIdx.x >> 6;
    const size_t base = (size_t)b * cC * cFHW + f;
    const size_t rbase = RAW ? (xoff + base) : base;
    float s = 0.f, ss = 0.f;
    for (int c = c4; c < cC; c += 4) {
        float v = RAW ? ldflex(x, rbase + (size_t)c * cFHW, isf)
                      : ((const float*)x)[base + (size_t)c * cFHW];
        s += v; ss += v * v;
    }
    __shared__ float S[4][64], SS[4][64];
    S[c4][l] = s; SS[c4][l] = ss;
    __syncthreads();
    const float sum  = S[0][l] + S[1][l] + S[2][l] + S[3][l];
    const float ssum = SS[0][l] + SS[1][l] + SS[2][l] + SS[3][l];
    const float mean = sum * (1.f / cC);
    const float var  = fmaxf(ssum * (1.f / cC) - mean * mean, 0.f);
    const float r = rsqrtf(var + 1e-6f);
    for (int c = c4; c < cC; c += 4) {
        float v = RAW ? ldflex(x, rbase + (size_t)c * cFHW, isf)
                      : ((const float*)x)[base + (size_t)c * cFHW];
        out[base + (size_t)c * cFHW] = w[c] * ((v - mean) * r) + bias[c];
    }
}

// ============================================================
// 1x1-conv GEMM v3: out[b,m,n] = sum_k Wt[k,m] * X[b,k,n]  (N=576)
// Wt pre-transposed K x M. 128(m) x 64(n) tile, 256 thr, 8x4 micro.
// 9 n-tiles exactly (no edge). M,K multiples of 128/16.
// EPI 0: f32 = acc; EPI 1: f32 = acc + bias_m + resRaw (flag dtype);
// EPI 2: f32 = acc + resF.
// ============================================================
template <int EPI>
__global__ __launch_bounds__(256) void conv_gemm(
    const float* __restrict__ Wt, const float* __restrict__ X, float* __restrict__ outp,
    const float* __restrict__ bias_m, const void* __restrict__ resRaw, size_t resOff,
    const float* __restrict__ resF, int M, int K, const int* __restrict__ flags)
{
    const int n0 = blockIdx.x * 64, m0 = blockIdx.y * 128, b = blockIdx.z;
    __shared__ __align__(16) float At[16][132];   // At[k][m]
    __shared__ __align__(16) float Bt[16][68];    // Bt[k][n]
    const int tid = threadIdx.x;
    const int tx = tid & 15, ty = tid >> 4;
    float acc[8][4] = {};
    const size_t xbase = (size_t)b * K * cFHW + n0;
    // staging maps
    const int akl0 = tid >> 5, amq0 = tid & 31;           // idx = tid
    const int akl1 = (tid + 256) >> 5, amq1 = tid & 31;   // idx = tid + 256
    const int bkl = tid >> 4, bnq = tid & 15;
    for (int k0 = 0; k0 < K; k0 += 16) {
        *(float4*)&At[akl0][amq0 * 4] = *(const float4*)(Wt + (size_t)(k0 + akl0) * M + m0 + amq0 * 4);
        *(float4*)&At[akl1][amq1 * 4] = *(const float4*)(Wt + (size_t)(k0 + akl1) * M + m0 + amq1 * 4);
        *(float4*)&Bt[bkl][bnq * 4]   = *(const float4*)(X + xbase + (size_t)(k0 + bkl) * cFHW + bnq * 4);
        __syncthreads();
        #pragma unroll
        for (int kk = 0; kk < 16; kk++) {
            float a[8], bb[4];
            *(float4*)&a[0] = *(const float4*)&At[kk][ty * 8];
            *(float4*)&a[4] = *(const float4*)&At[kk][ty * 8 + 4];
            *(float4*)&bb[0] = *(const float4*)&Bt[kk][tx * 4];
            #pragma unroll
            for (int i = 0; i < 8; i++)
                #pragma unroll
                for (int j = 0; j < 4; j++)
                    acc[i][j] += a[i] * bb[j];
        }
        __syncthreads();
    }
    const int isf = (EPI == 1) ? flags[0] : 1;
    #pragma unroll
    for (int i = 0; i < 8; i++) {
        const int m = m0 + ty * 8 + i;
        const size_t o = ((size_t)b * M + m) * cFHW + n0 + tx * 4;
        float4 v = make_float4(acc[i][0], acc[i][1], acc[i][2], acc[i][3]);
        if constexpr (EPI == 1) {
            const float bm = bias_m[m];
            v.x += bm + ldflex(resRaw, resOff + o + 0, isf);
            v.y += bm + ldflex(resRaw, resOff + o + 1, isf);
            v.z += bm + ldflex(resRaw, resOff + o + 2, isf);
            v.w += bm + ldflex(resRaw, resOff + o + 3, isf);
        } else if constexpr (EPI == 2) {
            const float4 rv = *(const float4*)&resF[o];
            v.x += rv.x; v.y += rv.y; v.z += rv.z; v.w += rv.w;
        }
        *(float4*)&outp[o] = v;
    }
}

// ============================================================
// attention stats: per (b_local,n,h) -> a1,m1,1/Z1,a2,m2,1/Z2
// ============================================================
__global__ __launch_bounds__(64) void attn_stats_kernel(
    const float* __restrict__ qkv, const float* __restrict__ tq, float* __restrict__ stats)
{
    const int idx = blockIdx.x;
    const int h = idx % cHD;
    const int bn = idx / cHD;
    const int n = bn & 3, b = bn >> 2;
    const int lane = threadIdx.x;
    const float* qrow = qkv + ((size_t)b * cC3 + n * cHD + h) * cFHW;
    const float* krow = qkv + ((size_t)b * cC3 + cC + n * cHD + h) * cFHW;
    float ssk = 0.f, mink = 3.0e38f, maxk = -3.0e38f;
    float ssq = 0.f, minq = 3.0e38f, maxq = -3.0e38f;
    for (int f = lane; f < cFHW; f += 64) {
        const float kv = krow[f]; ssk += kv * kv; maxk = fmaxf(maxk, kv); mink = fminf(mink, kv);
        const float qv = qrow[f]; ssq += qv * qv; maxq = fmaxf(maxq, qv); minq = fminf(minq, qv);
    }
    #pragma unroll
    for (int o = 1; o < 64; o <<= 1) {
        ssk += __shfl_xor(ssk, o, 64); ssq += __shfl_xor(ssq, o, 64);
        maxk = fmaxf(maxk, __shfl_xor(maxk, o, 64)); mink = fminf(mink, __shfl_xor(mink, o, 64));
        maxq = fmaxf(maxq, __shfl_xor(maxq, o, 64)); minq = fminf(minq, __shfl_xor(minq, o, 64));
    }
    const float qt = tq[(size_t)b * cC3 + n * 3 * cHD + h];
    const float kt = tq[(size_t)b * cC3 + n * 3 * cHD + cHD + h];
    const float sign1 = qt / fmaxf(fabsf(qt), 1e-12f);
    const float sign2 = kt / fmaxf(fabsf(kt), 1e-12f);
    const float a1 = sign1 / fmaxf(sqrtf(ssk), 1e-12f);
    const float a2 = sign2 / fmaxf(sqrtf(ssq), 1e-12f);
    const float m1 = fmaxf(a1 * maxk, a1 * mink);
    const float m2 = fmaxf(a2 * maxq, a2 * minq);
    float z1 = 0.f, z2 = 0.f;
    for (int f = lane; f < cFHW; f += 64) {
        z1 += expf(a1 * krow[f] - m1);
        z2 += expf(a2 * qrow[f] - m2);
    }
    #pragma unroll
    for (int o = 1; o < 64; o <<= 1) { z1 += __shfl_xor(z1, o, 64); z2 += __shfl_xor(z2, o, 64); }
    if (lane == 0) {
        float* sp = stats + (size_t)idx * 6;
        sp[0] = a1; sp[1] = m1; sp[2] = 1.f / z1;
        sp[3] = a2; sp[4] = m2; sp[5] = 1.f / z2;
    }
}

// ============================================================
// attention GEMM: img[b, n*192+h, g] = sum_f (P1+P2)[h,f] * v[g,f]
// ============================================================
__global__ __launch_bounds__(256) void attn_gemm_kernel(
    const float* __restrict__ qkv, const float* __restrict__ stats, float* __restrict__ img)
{
    const int h0 = blockIdx.x * 64, g0 = blockIdx.y * 64, bn = blockIdx.z;
    const int b = bn >> 2, n = bn & 3;
    __shared__ __align__(16) float Pt[16][68];
    __shared__ __align__(16) float Vt[16][68];
    __shared__ float st[6][64];
    const int tid = threadIdx.x;
    const int ty = tid >> 4, tx = tid & 15;
    if (tid < 64) {
        const float* sp = stats + ((size_t)bn * cHD + h0 + tid) * 6;
        #pragma unroll
        for (int j = 0; j < 6; j++) st[j][tid] = sp[j];
    }
    __syncthreads();
    float acc[4][4] = {};
    const size_t qbase = ((size_t)b * cC3 + n * cHD + h0) * cFHW;
    const size_t kbase = ((size_t)b * cC3 + cC + n * cHD + h0) * cFHW;
    const size_t vbase = ((size_t)b * cC3 + 2 * cC + n * cHD + g0) * cFHW;
    for (int f0 = 0; f0 < cFHW; f0 += 16) {
        const int col = tid & 15, row = tid >> 4;
        #pragma unroll
        for (int p = 0; p < 4; p++) {
            const int r = row + p * 16;
            const float kv = qkv[kbase + (size_t)r * cFHW + f0 + col];
            const float qv = qkv[qbase + (size_t)r * cFHW + f0 + col];
            Pt[col][r] = expf(st[0][r] * kv - st[1][r]) * st[2][r]
                       + expf(st[3][r] * qv - st[4][r]) * st[5][r];
            Vt[col][r] = qkv[vbase + (size_t)r * cFHW + f0 + col];
        }
        __syncthreads();
        #pragma unroll
        for (int kk = 0; kk < 16; kk++) {
            const float4 av = *(const float4*)&Pt[kk][ty * 4];
            const float4 bv = *(const float4*)&Vt[kk][tx * 4];
            acc[0][0] += av.x * bv.x; acc[0][1] += av.x * bv.y; acc[0][2] += av.x * bv.z; acc[0][3] += av.x * bv.w;
            acc[1][0] += av.y * bv.x; acc[1][1] += av.y * bv.y; acc[1][2] += av.y * bv.z; acc[1][3] += av.y * bv.w;
            acc[2][0] += av.z * bv.x; acc[2][1] += av.z * bv.y; acc[2][2] += av.z * bv.z; acc[2][3] += av.z * bv.w;
            acc[3][0] += av.w * bv.x; acc[3][1] += av.w * bv.y; acc[3][2] += av.w * bv.z; acc[3][3] += av.w * bv.w;
        }
        __syncthreads();
    }
    #pragma unroll
    for (int i = 0; i < 4; i++) {
        const size_t o = ((size_t)b * cC + n * cHD + h0 + ty * 4 + i) * cHD + g0 + tx * 4;
        *(float4*)&img[o] = make_float4(acc[i][0], acc[i][1], acc[i][2], acc[i][3]);
    }
}

// ============================================================
// y GEMM (A * B^T): y[b,m,n] = sum_k img[b,m,k]*o2w[n,k] + o2b[n]
// ============================================================
__global__ __launch_bounds__(256) void y_gemm_kernel(
    const float* __restrict__ A, const float* __restrict__ Bw,
    const float* __restrict__ bias_n, float* __restrict__ out)
{
    const int n0 = blockIdx.x * 64, m0 = blockIdx.y * 64, b = blockIdx.z;
    __shared__ __align__(16) float At[16][68];
    __shared__ __align__(16) float Bt[16][68];
    const int tid = threadIdx.x;
    const int ty = tid >> 4, tx = tid & 15;
    float acc[4][4] = {};
    for (int k0 = 0; k0 < cHD; k0 += 16) {
        const int col = tid & 15, row = tid >> 4;
        #pragma unroll
        for (int p = 0; p < 4; p++) {
            const int r = row + p * 16;
            At[col][r] = A[((size_t)b * cC + m0 + r) * cHD + k0 + col];
            Bt[col][r] = Bw[(size_t)(n0 + r) * cHD + k0 + col];
        }
        __syncthreads();
        #pragma unroll
        for (int kk = 0; kk < 16; kk++) {
            const float4 av = *(const float4*)&At[kk][ty * 4];
            const float4 bv = *(const float4*)&Bt[kk][tx * 4];
            acc[0][0] += av.x * bv.x; acc[0][1] += av.x * bv.y; acc[0][2] += av.x * bv.z; acc[0][3] += av.x * bv.w;
            acc[1][0] += av.y * bv.x; acc[1][1] += av.y * bv.y; acc[1][2] += av.y * bv.z; acc[1][3] += av.y * bv.w;
            acc[2][0] += av.z * bv.x; acc[2][1] += av.z * bv.y; acc[2][2] += av.z * bv.z; acc[2][3] += av.z * bv.w;
            acc[3][0] += av.w * bv.x; acc[3][1] += av.w * bv.y; acc[3][2] += av.w * bv.z; acc[3][3] += av.w * bv.w;
        }
        __syncthreads();
    }
    #pragma unroll
    for (int i = 0; i < 4; i++) {
        const size_t o = ((size_t)b * cC + m0 + ty * 4 + i) * cFHW + n0 + tx * 4;
        float4 v;
        v.x = acc[i][0] + bias_n[n0 + tx * 4 + 0];
        v.y = acc[i][1] + bias_n[n0 + tx * 4 + 1];
        v.z = acc[i][2] + bias_n[n0 + tx * 4 + 2];
        v.w = acc[i][3] + bias_n[n0 + tx * 4 + 3];
        *(float4*)&out[o] = v;
    }
}

// ============================================================
// depthwise 3x3 SAME + exact GELU; one block per (c,b_local); fp32
// ============================================================
__global__ __launch_bounds__(576) void dwconv_gelu_kernel(
    const float* __restrict__ X, const float* __restrict__ w, float* __restrict__ Y)
{
    const int c = blockIdx.x, b = blockIdx.y;
    __shared__ float t[26][28];
    const int tid = threadIdx.x;
    float* tf = &t[0][0];
    for (int i = tid; i < 26 * 28; i += 576) tf[i] = 0.f;
    __syncthreads();
    const size_t base = ((size_t)b * cC + c) * cFHW;
    const int x = tid % 24, y = tid / 24;
    t[y + 1][x + 1] = X[base + tid];
    __syncthreads();
    float w9[9];
    #pragma unroll
    for (int j = 0; j < 9; j++) w9[j] = w[c * 9 + j];
    float s = 0.f;
    #pragma unroll
    for (int dy = 0; dy < 3; dy++)
        #pragma unroll
        for (int dx = 0; dx < 3; dx++)
            s += w9[dy * 3 + dx] * t[y + dy][x + dx];
    const float g = 0.5f * s * (1.f + erff(s * 0.70710678118654752f));
    Y[base + tid] = g;
}

// ============================================================
extern "C" void kernel_launch(void* const* d_in, const int* in_sizes, int n_in,
                              void* d_out, int out_size, void* d_ws, size_t ws_size,
                              hipStream_t stream)
{
    // ---- workspace layout (fp32, 256B-aligned) ----
    char* p = (char*)d_ws;
    auto alloc = [&](size_t elems) { char* r = p; p += (elems * 4 + 255) & ~(size_t)255; return (float*)r; };
    float* c_txt   = alloc((size_t)cB * cD);
    float* c_fnw   = alloc(cC);
    float* c_fnb   = alloc(cC);
    float* c_gnw   = alloc(cD);
    float* c_gnb   = alloc(cD);
    float* t_qkvw  = alloc((size_t)cC3 * cC);    // transposed K x M
    float* c_qkvtw = alloc((size_t)cC3 * cD);
    float* t_oiw   = alloc((size_t)cC * cC);     // transposed
    float* c_oib   = alloc(cC);
    float* c_oi2w  = alloc((size_t)cFHW * cHD);
    float* c_oi2b  = alloc(cFHW);
    float* c_ffnw  = alloc(cC);
    float* c_ffnb  = alloc(cC);
    float* t_fc1   = alloc((size_t)cC * cC);     // transposed
    float* c_dw    = alloc(cC * 9);
    float* t_fc2   = alloc((size_t)cC * cC);     // transposed
    int*   flags   = (int*)alloc(64);
    float* tq      = alloc((size_t)cB * cC3);
    float* stats   = alloc((size_t)cB * cNH * cHD * 6);      // sized for Q=32
    // fixed part used so far:
    const size_t fixedBytes = (size_t)(p - (char*)d_ws);
    // choose batch-chunk Q from remaining workspace: need Q*(3 slotA + imgC/F frac)
    // per-Q bytes: slotA = 3*Q*C*F*4; slotC = Q*C*HD*4
    auto needBytes = [&](int Q) {
        return fixedBytes + (size_t)Q * cC * cFHW * 4ull * 3ull + (size_t)Q * cC * cHD * 4ull + 4096;
    };
    int Q = 8;
    if (ws_size >= needBytes(32)) Q = 32;
    else if (ws_size >= needBytes(16)) Q = 16;
    const size_t QCF = (size_t)Q * cC * cFHW;
    float* slotA = alloc(3 * QCF);                // q,k,v -> out,za,zb
    float* slotC = alloc((size_t)Q * cC * cHD);   // imgq
    float* A0 = slotA, *A1 = slotA + QCF, *A2 = slotA + 2 * QCF;
    (void)in_sizes; (void)n_in; (void)out_size;

    // ---- dtype probe ----
    detect_kernel<<<1, 1, 0, stream>>>((const u16*)d_in[2], flags);

    // ---- canonicalize 12 small arrays in one launch ----
    FlatDesc fd;
    const void* srcs[12] = { d_in[1], d_in[2], d_in[3], d_in[4], d_in[5], d_in[7],
                             d_in[9], d_in[10], d_in[11], d_in[12], d_in[13], d_in[15] };
    float* dsts[12]      = { c_txt, c_fnw, c_fnb, c_gnw, c_gnb, c_qkvtw,
                             c_oib, c_oi2w, c_oi2b, c_ffnw, c_ffnb, c_dw };
    const int ns[12]     = { cB * cD, cC, cC, cD, cD, cC3 * cD,
                             cC, cFHW * cHD, cFHW, cC, cC, cC * 9 };
    int tot = 0;
    for (int i = 0; i < 12; i++) { fd.src[i] = srcs[i]; fd.dst[i] = dsts[i]; fd.off[i] = tot; tot += ns[i]; }
    fd.off[12] = tot;
    flatten_kernel<<<(tot + 255) / 256, 256, 0, stream>>>(fd, flags);

    // ---- transpose the 4 big weights (Wt[k][m] = W[m][k]) ----
    transpose_kernel<<<dim3(cC / 32, cC3 / 32), 256, 0, stream>>>(d_in[6],  t_qkvw, cC3, cC, flags);
    transpose_kernel<<<dim3(cC / 32, cC / 32),  256, 0, stream>>>(d_in[8],  t_oiw,  cC,  cC, flags);
    transpose_kernel<<<dim3(cC / 32, cC / 32),  256, 0, stream>>>(d_in[14], t_fc1,  cC,  cC, flags);
    transpose_kernel<<<dim3(cC / 32, cC / 32),  256, 0, stream>>>(d_in[16], t_fc2,  cC,  cC, flags);

    txt_qkv_kernel<<<cB, 256, 0, stream>>>(c_txt, c_gnw, c_gnb, c_qkvtw, tq);

    // ---- per-chunk pipeline (batch elements are fully independent) ----
    // slotB (xln / y) lives in d_out: exactly Q*C*F floats per chunk, dead
    // before the final EPI2 write to the same region.
    for (int q0 = 0; q0 < cB; q0 += Q) {
        const size_t off = (size_t)q0 * cC * cFHW;
        float* slotB = (float*)d_out + off;
        ln2d_kernel<1><<<dim3(9, Q), 256, 0, stream>>>(d_in[0], off, c_fnw, c_fnb, slotB, flags);
        conv_gemm<0><<<dim3(9, cC3 / 128, Q), 256, 0, stream>>>(t_qkvw, slotB, slotA,
                                                                nullptr, nullptr, 0, nullptr, cC3, cC, flags);
        attn_stats_kernel<<<Q * cNH * cHD, 64, 0, stream>>>(slotA, tq + (size_t)q0 * cC3, stats);
        attn_gemm_kernel<<<dim3(3, 3, Q * cNH), 256, 0, stream>>>(slotA, stats, slotC);
        y_gemm_kernel<<<dim3(9, 12, Q), 256, 0, stream>>>(slotC, c_oi2w, c_oi2b, slotB);
        conv_gemm<1><<<dim3(9, cC / 128, Q), 256, 0, stream>>>(t_oiw, slotB, A0,
                                                               c_oib, d_in[0], off, nullptr, cC, cC, flags);
        ln2d_kernel<0><<<dim3(9, Q), 256, 0, stream>>>(A0, 0, c_ffnw, c_ffnb, A1, flags);
        conv_gemm<0><<<dim3(9, cC / 128, Q), 256, 0, stream>>>(t_fc1, A1, A2,
                                                               nullptr, nullptr, 0, nullptr, cC, cC, flags);
        dwconv_gelu_kernel<<<dim3(cC, Q), 576, 0, stream>>>(A2, c_dw, A1);
        conv_gemm<2><<<dim3(9, cC / 128, Q), 256, 0, stream>>>(t_fc2, A1, (float*)d_out + off,
                                                               nullptr, nullptr, 0, A0, cC, cC, flags);
    }
}